// Round 10
// baseline (187.417 us; speedup 1.0000x reference)
//
#include <hip/hip_runtime.h>

typedef unsigned short u16;
typedef unsigned int u32;
typedef short short8 __attribute__((ext_vector_type(8)));
typedef float f32x4 __attribute__((ext_vector_type(4)));

#define KEEP(x) asm volatile("" :: "v"(x))
#define BN_EPS 1e-5f

__device__ __forceinline__ u16 f2bf(float x) {
  union { float f; u32 u; } v;
  v.f = x;
  u32 r = v.u + 0x7FFFu + ((v.u >> 16) & 1u);
  return (u16)(r >> 16);
}

// ---------------- gcalc_all: single pre-kernel (81 blocks) ----------------
// blocks 0..63  : (b = bid>>2, och0 = (bid&3)*64) -> G[b][ch][96] + bias1[b][ch]
// blocks 64..79 : w2b = bf16(w2 * s2)
// block  80     : w3b (rows>=50 zero) + b2p
__global__ __launch_bounds__(256, 2)
void gcalc_all(const float* __restrict__ features, const int* __restrict__ category,
               const float* __restrict__ cat_embed,
               const float* __restrict__ w1, const float* __restrict__ b1,
               const float* __restrict__ g1, const float* __restrict__ be1,
               const float* __restrict__ m1, const float* __restrict__ v1,
               const float* __restrict__ w2, const float* __restrict__ g2,
               const float* __restrict__ b2, const float* __restrict__ be2,
               const float* __restrict__ m2, const float* __restrict__ v2,
               const float* __restrict__ w3,
               u16* __restrict__ G, float* __restrict__ bias1,
               u16* __restrict__ w2b, u16* __restrict__ w3b, float* __restrict__ b2p)
{
  __shared__ u16 Fs[64 * 392];
  const int bid = blockIdx.x;
  const int tid = threadIdx.x;

  if (bid < 64) {
    const int b    = bid >> 2;
    const int och0 = (bid & 3) * 64;
    const int lane = tid & 63;
    const int wv   = tid >> 6;
    const int lr   = lane & 15;
    const int lk   = (lane >> 4) * 8;
    const int r0   = (lane >> 4) * 4;

    const f32x4* F4 = (const f32x4*)(features + b * 24576);
    #pragma unroll
    for (int it = 0; it < 24; ++it) {
      int idx = tid + 256 * it;
      int c = idx / 96;
      int d4 = idx - c * 96;
      f32x4 v = F4[c * 96 + d4];
      u32 lo = (u32)f2bf(v[0]) | ((u32)f2bf(v[1]) << 16);
      u32 hi = (u32)f2bf(v[2]) | ((u32)f2bf(v[3]) << 16);
      *(uint2*)&Fs[c * 392 + d4 * 4] = make_uint2(lo, hi);
    }

    if (tid < 64) {
      int o = och0 + tid;
      float s1 = g1[o] * rsqrtf(v1[o] + BN_EPS);
      float acc = (b1[o] - m1[o]) * s1 + be1[o];
      const float* wr = w1 + o * 451 + 384;
      const float* ce = cat_embed + category[b] * 64;
      #pragma unroll 8
      for (int j = 0; j < 64; ++j) acc += wr[j] * s1 * ce[j];
      bias1[b * 256 + o] = acc;
      u16* Go = G + (b * 256 + o) * 96;
      Go[64] = f2bf(wr[64] * s1);
      Go[65] = f2bf(wr[65] * s1);
      Go[66] = f2bf(wr[66] * s1);
      #pragma unroll
      for (int k = 67; k < 96; ++k) Go[k] = 0;
    }
    __syncthreads();

    const int ch = och0 + wv * 16 + lr;
    const float s1 = g1[ch] * rsqrtf(v1[ch] + BN_EPS);
    f32x4 acc[4];
    {
      f32x4 z = {0.f, 0.f, 0.f, 0.f};
      #pragma unroll
      for (int m = 0; m < 4; ++m) acc[m] = z;
    }
    #pragma unroll
    for (int ks = 0; ks < 12; ++ks) {
      const float* wr = w1 + ch * 451 + ks * 32 + lk;
      short8 bv;
      #pragma unroll
      for (int e = 0; e < 8; ++e) bv[e] = (short)f2bf(wr[e] * s1);
      #pragma unroll
      for (int m = 0; m < 4; ++m) {
        short8 av = *(const short8*)(&Fs[(m * 16 + lr) * 392 + ks * 32 + lk]);
        acc[m] = __builtin_amdgcn_mfma_f32_16x16x32_bf16(av, bv, acc[m], 0, 0, 0);
      }
    }
    #pragma unroll
    for (int m = 0; m < 4; ++m)
      #pragma unroll
      for (int r = 0; r < 4; ++r)
        G[(b * 256 + ch) * 96 + m * 16 + r0 + r] = f2bf(acc[m][r]);

  } else if (bid < 80) {
    int base = (bid - 64) * 4096;
    #pragma unroll
    for (int e = 0; e < 16; ++e) {
      int i = base + e * 256 + tid;
      int o = i >> 8;
      float s2 = g2[o] * rsqrtf(v2[o] + BN_EPS);
      w2b[i] = f2bf(w2[i] * s2);
    }
  } else {
    #pragma unroll
    for (int e = 0; e < 64; ++e) {
      int i = e * 256 + tid;
      int o = i >> 8;
      w3b[i] = (o < 50) ? f2bf(w3[i]) : (u16)0;
    }
    {
      float s2 = g2[tid] * rsqrtf(v2[tid] + BN_EPS);
      b2p[tid] = (b2[tid] - m2[tid]) * s2 + be2[tid];
    }
  }
}

// ---------------- fused main kernel ----------------
// One block = 128 points, 512 threads = 8 waves.
// knn (shuffle merge) -> P_ext[128][96]. GEMM1 (K=96). GEMM2.
// GEMM3: wave = 16 rows x 64 cols -> per-wave LDS patch (own rows) -> dense stores.
// h-buffer XOR-swizzled: col ^= ((row>>2)&7)<<3 (u16), g ^= (row>>2)&7 (b128).
#define LDP 104
#define LDH 264

__global__ __launch_bounds__(512, 4)
void fused_kernel(const float* __restrict__ centers, const float* __restrict__ pc,
                  const u16* __restrict__ G, const float* __restrict__ bias1,
                  const u16* __restrict__ w2b, const u16* __restrict__ w3b,
                  const float* __restrict__ b2p, const float* __restrict__ b3,
                  float* __restrict__ out)
{
  __shared__ u16 hbuf[128 * LDH];   // 67584 B; aliases: P_ext @0; GEMM3 patches per-wave
  __shared__ float centl[192];
  __shared__ float pcl[384];

  // bijective XCD swizzle (1024 blocks, 8 XCDs)
  const int bx   = ((blockIdx.x & 7) << 7) | (blockIdx.x >> 3);
  const int b    = bx >> 6;
  const int n0   = (bx & 63) << 7;
  const int tid  = threadIdx.x;
  const int lane = tid & 63;
  const int wv   = tid >> 6;
  const int lr   = lane & 15;
  const int lk   = (lane >> 4) * 8;
  const int r0   = (lane >> 4) * 4;

  u16* Pm = hbuf;  // [128][LDP]

  // ---- preload this wave's G fragments (plain loads; complete during knn) ----
  short8 bvG[3][2];
  #pragma unroll
  for (int ks = 0; ks < 3; ++ks)
    #pragma unroll
    for (int n = 0; n < 2; ++n)
      bvG[ks][n] = *(const short8*)(G + (b * 256 + wv * 32 + n * 16 + lr) * 96 + ks * 32 + lk);

  // ---- zero P_ext + stage centers/pc ----
  {
    u32* Pw = (u32*)Pm;
    #pragma unroll
    for (int i = 0; i < 13; ++i) Pw[tid + 512 * i] = 0;
  }
  if (tid < 192) centl[tid] = centers[b * 192 + tid];
  if (tid < 384) pcl[tid] = pc[(b * 8192 + n0) * 3 + tid];
  __syncthreads();  // S1

  // ---- knn: 4 lanes/point scan 16 centers each, merge via shuffles ----
  {
    int p = tid >> 2, c4 = tid & 3;
    float px = pcl[p * 3 + 0], py = pcl[p * 3 + 1], pz = pcl[p * 3 + 2];
    float p2 = px * px + py * py + pz * pz;
    float bd0 = 3.4e38f, bd1 = 3.4e38f, bd2 = 3.4e38f;
    int bi0 = 0, bi1 = 0, bi2 = 0;
    int j0 = c4 * 16;
    for (int j = j0; j < j0 + 16; ++j) {
      float cx = centl[j * 3 + 0], cy = centl[j * 3 + 1], cz = centl[j * 3 + 2];
      float dotv = px * cx + py * cy + pz * cz;
      float c2 = cx * cx + cy * cy + cz * cz;
      float d2 = (p2 + c2) - 2.f * dotv;
      if (d2 < bd2) {
        if (d2 < bd1) {
          if (d2 < bd0) { bd2 = bd1; bi2 = bi1; bd1 = bd0; bi1 = bi0; bd0 = d2; bi0 = j; }
          else          { bd2 = bd1; bi2 = bi1; bd1 = d2; bi1 = j; }
        } else          { bd2 = d2; bi2 = j; }
      }
    }
    // merge the 4 lanes of this point's group (chunk order preserves tie semantics)
    float md0 = 3.4e38f, md1 = 3.4e38f, md2 = 3.4e38f;
    int mi0 = 0, mi1 = 0, mi2 = 0;
    auto INS = [&](float d, int j) {
      if (d < md2) {
        if (d < md1) {
          if (d < md0) { md2 = md1; mi2 = mi1; md1 = md0; mi1 = mi0; md0 = d; mi0 = j; }
          else         { md2 = md1; mi2 = mi1; md1 = d; mi1 = j; }
        } else         { md2 = d; mi2 = j; }
      }
    };
    int gl = lane & ~3;
    #pragma unroll
    for (int c = 0; c < 4; ++c) {
      int src = gl + c;
      float d0 = __shfl(bd0, src), d1 = __shfl(bd1, src), d2 = __shfl(bd2, src);
      int   e0 = __shfl(bi0, src), e1 = __shfl(bi1, src), e2 = __shfl(bi2, src);
      INS(d0, e0); INS(d1, e1); INS(d2, e2);
    }
    if (c4 == 0) {
      float dd0 = sqrtf(fmaxf(md0, 1e-12f));
      float dd1 = sqrtf(fmaxf(md1, 1e-12f));
      float dd2 = sqrtf(fmaxf(md2, 1e-12f));
      float u0 = 1.f / (dd0 + 1e-8f);
      float u1 = 1.f / (dd1 + 1e-8f);
      float u2 = 1.f / (dd2 + 1e-8f);
      float inv = 1.f / (u0 + u1 + u2);
      u16* Pr = Pm + p * LDP;
      Pr[mi0] = f2bf(u0 * inv);
      Pr[mi1] = f2bf(u1 * inv);
      Pr[mi2] = f2bf(u2 * inv);
      Pr[64] = f2bf(px);
      Pr[65] = f2bf(py);
      Pr[66] = f2bf(pz);
    }
  }
  KEEP(bvG[0][0]); KEEP(bvG[0][1]); KEEP(bvG[1][0]);
  KEEP(bvG[1][1]); KEEP(bvG[2][0]); KEEP(bvG[2][1]);
  __syncthreads();  // S2

  // ---- GEMM1: P_ext [128][96] x G-stripe -> 32 ch/wave ----
  f32x4 acc[8][2];
  {
    f32x4 z = {0.f, 0.f, 0.f, 0.f};
    #pragma unroll
    for (int m = 0; m < 8; ++m) { acc[m][0] = z; acc[m][1] = z; }
  }
  #pragma unroll
  for (int ks = 0; ks < 3; ++ks) {
    short8 av[8];
    #pragma unroll
    for (int m = 0; m < 8; ++m)
      av[m] = *(const short8*)(&Pm[(m * 16 + lr) * LDP + ks * 32 + lk]);
    #pragma unroll
    for (int m = 0; m < 8; ++m)
      #pragma unroll
      for (int n = 0; n < 2; ++n)
        acc[m][n] = __builtin_amdgcn_mfma_f32_16x16x32_bf16(av[m], bvG[ks][n], acc[m][n], 0, 0, 0);
  }
  __syncthreads();  // S3 (P_ext dead)

  // ---- preload first 4 k-steps of w2 (plain loads across epi1) ----
  short8 w2f[4][2];
  #pragma unroll
  for (int ks = 0; ks < 4; ++ks)
    #pragma unroll
    for (int n = 0; n < 2; ++n)
      w2f[ks][n] = *(const short8*)(w2b + (wv * 32 + n * 16 + lr) * 256 + ks * 32 + lk);

  // ---- epilogue 1: bias1 + relu -> h1 (swizzled) ----
  #pragma unroll
  for (int n = 0; n < 2; ++n) {
    float bb = bias1[b * 256 + wv * 32 + n * 16 + lr];
    #pragma unroll
    for (int m = 0; m < 8; ++m)
      #pragma unroll
      for (int r = 0; r < 4; ++r) {
        float v = acc[m][n][r] + bb;
        v = v > 0.f ? v : 0.f;
        int row = m * 16 + r0 + r;
        int col = (wv * 32 + n * 16 + lr) ^ (((row >> 2) & 7) << 3);
        hbuf[row * LDH + col] = f2bf(v);
      }
  }
  KEEP(w2f[0][0]); KEEP(w2f[0][1]); KEEP(w2f[1][0]); KEEP(w2f[1][1]);
  KEEP(w2f[2][0]); KEEP(w2f[2][1]); KEEP(w2f[3][0]); KEEP(w2f[3][1]);
  __syncthreads();  // S4

  // ---- GEMM2: h1 [128][256] x w2b-stripe -> h2 ----
  {
    f32x4 z = {0.f, 0.f, 0.f, 0.f};
    #pragma unroll
    for (int m = 0; m < 8; ++m) { acc[m][0] = z; acc[m][1] = z; }
  }
  #pragma unroll
  for (int ks = 0; ks < 8; ++ks) {
    short8 bv[2];
    if (ks < 4) { bv[0] = w2f[ks][0]; bv[1] = w2f[ks][1]; }
    else {
      #pragma unroll
      for (int n = 0; n < 2; ++n)
        bv[n] = *(const short8*)(w2b + (wv * 32 + n * 16 + lr) * 256 + ks * 32 + lk);
    }
    short8 av[8];
    #pragma unroll
    for (int m = 0; m < 8; ++m) {
      int row = m * 16 + lr;
      int g = (ks * 4 + (lane >> 4)) ^ ((row >> 2) & 7);
      av[m] = *(const short8*)(&hbuf[row * LDH + g * 8]);
    }
    #pragma unroll
    for (int m = 0; m < 8; ++m)
      #pragma unroll
      for (int n = 0; n < 2; ++n)
        acc[m][n] = __builtin_amdgcn_mfma_f32_16x16x32_bf16(av[m], bv[n], acc[m][n], 0, 0, 0);
  }
  __syncthreads();  // S5

  // ---- epilogue 2: b2p + relu -> h2 in place (swizzled) ----
  #pragma unroll
  for (int n = 0; n < 2; ++n) {
    float bb = b2p[wv * 32 + n * 16 + lr];
    #pragma unroll
    for (int m = 0; m < 8; ++m)
      #pragma unroll
      for (int r = 0; r < 4; ++r) {
        float v = acc[m][n][r] + bb;
        v = v > 0.f ? v : 0.f;
        int row = m * 16 + r0 + r;
        int col = (wv * 32 + n * 16 + lr) ^ (((row >> 2) & 7) << 3);
        hbuf[row * LDH + col] = f2bf(v);
      }
  }
  __syncthreads();  // S6

  // ---- GEMM3: wave wv owns rows [wv*16, wv*16+16), ALL 64 cols ----
  {
    f32x4 acc3[4];
    {
      f32x4 z = {0.f, 0.f, 0.f, 0.f};
      #pragma unroll
      for (int n = 0; n < 4; ++n) acc3[n] = z;
    }
    const int row = wv * 16 + lr;
    #pragma unroll
    for (int ks = 0; ks < 8; ++ks) {
      int g = (ks * 4 + (lane >> 4)) ^ ((row >> 2) & 7);
      short8 av = *(const short8*)(&hbuf[row * LDH + g * 8]);
      #pragma unroll
      for (int n = 0; n < 4; ++n) {
        short8 bv = *(const short8*)(w3b + (n * 16 + lr) * 256 + ks * 32 + lk);
        acc3[n] = __builtin_amdgcn_mfma_f32_16x16x32_bf16(av, bv, acc3[n], 0, 0, 0);
      }
    }
    // stage into this wave's OWN 16 rows of hbuf — GUARD c<50 (stride-52 rows:
    // unguarded c=52..63 writes alias row rr+1 cols 0..11 — the R8/R9 bug)
    float* patch = (float*)(hbuf + wv * 16 * LDH);   // [16][52] f32 = 3328 B < 8448 B
    #pragma unroll
    for (int n = 0; n < 4; ++n) {
      int c = n * 16 + lr;
      if (c < 50) {
        float b3v = b3[c];
        #pragma unroll
        for (int r = 0; r < 4; ++r)
          patch[(r0 + r) * 52 + c] = acc3[n][r] + b3v;
      }
    }
    // dense coalesced store: 16 rows x 50 ch = 800 contiguous floats
    float* outb = out + (size_t)(b * 8192 + n0 + wv * 16) * 50;
    #pragma unroll
    for (int it = 0; it < 13; ++it) {
      int f = it * 64 + lane;
      if (f < 800) {
        int rr = (f * 5243) >> 18;     // f / 50
        int cc = f - rr * 50;
        outb[f] = patch[rr * 52 + cc];
      }
    }
  }
}

extern "C" void kernel_launch(void* const* d_in, const int* in_sizes, int n_in,
                              void* d_out, int out_size, void* d_ws, size_t ws_size,
                              hipStream_t stream) {
  const float* features  = (const float*)d_in[0];
  const float* centers   = (const float*)d_in[1];
  const float* pc        = (const float*)d_in[2];
  const int*   category  = (const int*)d_in[3];
  const float* cat_embed = (const float*)d_in[4];
  const float* w1  = (const float*)d_in[5];
  const float* b1  = (const float*)d_in[6];
  const float* g1  = (const float*)d_in[7];
  const float* be1 = (const float*)d_in[8];
  const float* m1  = (const float*)d_in[9];
  const float* v1  = (const float*)d_in[10];
  const float* w2  = (const float*)d_in[11];
  const float* b2  = (const float*)d_in[12];
  const float* g2  = (const float*)d_in[13];
  const float* be2 = (const float*)d_in[14];
  const float* m2  = (const float*)d_in[15];
  const float* v2  = (const float*)d_in[16];
  const float* w3  = (const float*)d_in[17];
  const float* b3  = (const float*)d_in[18];
  float* out = (float*)d_out;

  char* ws = (char*)d_ws;
  u16*   w2b   = (u16*)(ws);              // 131072 B
  u16*   w3b   = (u16*)(ws + 131072);     //  32768 B
  float* b2p   = (float*)(ws + 163840);   //   1024 B
  u16*   G     = (u16*)(ws + 164864);     // 786432 B
  float* bias1 = (float*)(ws + 951296);   //  16384 B -> ends 967680

  gcalc_all<<<81, 256, 0, stream>>>(features, category, cat_embed,
                                    w1, b1, g1, be1, m1, v1,
                                    w2, g2, b2, be2, m2, v2, w3,
                                    G, bias1, w2b, w3b, b2p);

  fused_kernel<<<1024, 512, 0, stream>>>(centers, pc, G, bias1,
                                         w2b, w3b, b2p, b3, out);
}